// Round 12
// baseline (95.630 us; speedup 1.0000x reference)
//
#include <hip/hip_runtime.h>
#include <math.h>

#define B_ 2
#define U_ 32
#define V_ 2048
#define IN_ 256
#define ST_ 512
#define H_ 8
#define BU_ 64
#define NR_ 512

// ws layout (float offsets)
#define WS_SLN   0u          // [B][V][IN]      1048576
#define WS_SLNT  1048576u    // [B][IN][V]      1048576
#define WS_SCALE 2097152u    // [BU][2560]      163840  (q:0 k:512 v:768 e:1024 f1:1536 f2:2048)
#define WS_T     2260992u    // [NR][IN]        131072
#define WS_CB    2392064u    // [NR]            512
#define WS_SSUMP 2392576u    // [NR][8]         4096
#define WS_CTXP  2396672u    // [8][NR][IN]     1048576
#define WS_AO    3445248u    // [BU][512]       32768
#define WS_H2    3478016u    // [BU][512]       32768
#define WS_AOP   3510784u    // [4][BU][512]    131072

__device__ __forceinline__ float wsum(float v){
  #pragma unroll
  for(int m=32;m>0;m>>=1) v += __shfl_xor(v, m, 64);
  return v;
}

#define FMA4(A, t, S) { A.x += (t)*(S).x; A.y += (t)*(S).y; A.z += (t)*(S).z; A.w += (t)*(S).w; }

// ---------------- K1: fused sender-LN+transpose (blocks 0..127) and scales GEMM (blocks 128..447) ----------------
__global__ __launch_bounds__(256) void k_pre(const float* __restrict__ snd,
    const float* __restrict__ g, const float* __restrict__ bb,
    const float* __restrict__ codes,
    const float* __restrict__ Cq, const float* __restrict__ Ck, const float* __restrict__ Cv,
    const float* __restrict__ Ce, const float* __restrict__ C1, const float* __restrict__ C2,
    float* __restrict__ ws){
  __shared__ float tile[32][261];
  __shared__ float cds[8][256];
  const int tid = threadIdx.x;
  if(blockIdx.x < 128){
    const int wave = tid>>6, lane = tid&63;
    const int rowbase = blockIdx.x * 32;
    const int b = rowbase >> 11, vloc = rowbase & 2047;
    float4 gg  = *(const float4*)(g  + lane*4);
    float4 bbv = *(const float4*)(bb + lane*4);
    for(int it=0; it<8; ++it){
      int rl = it*4 + wave;
      int r  = rowbase + rl;
      float4 x = *(const float4*)(snd + (size_t)r*IN_ + lane*4);
      float s = x.x+x.y+x.z+x.w;
      float q = x.x*x.x+x.y*x.y+x.z*x.z+x.w*x.w;
      s = wsum(s); q = wsum(q);
      float mu = s*(1.0f/256.0f);
      float rv = rsqrtf(q*(1.0f/256.0f) - mu*mu + 1e-5f);
      float4 y;
      y.x = (x.x-mu)*rv*gg.x + bbv.x;
      y.y = (x.y-mu)*rv*gg.y + bbv.y;
      y.z = (x.z-mu)*rv*gg.z + bbv.z;
      y.w = (x.w-mu)*rv*gg.w + bbv.w;
      *(float4*)(ws + WS_SLN + (size_t)r*IN_ + lane*4) = y;
      tile[rl][lane*4+0] = y.x;
      tile[rl][lane*4+1] = y.y;
      tile[rl][lane*4+2] = y.z;
      tile[rl][lane*4+3] = y.w;
    }
    __syncthreads();
    const int vh = tid & 31;
    const int ibase = (tid >> 5);
    for(int it=0; it<32; ++it){
      int i = it*8 + ibase;
      ws[WS_SLNT + ((size_t)b*IN_ + i)*V_ + vloc + vh] = tile[vh][i];
    }
  } else {
    const int idx = blockIdx.x - 128;
    const int cg = idx % 40, bg = idx / 40;
    #pragma unroll
    for(int j=0;j<8;++j){
      int fi = j*256 + tid;
      cds[fi>>8][fi&255] = codes[(size_t)(bg*8)*256 + fi];
    }
    __syncthreads();
    const int q = tid & 3;
    const int col = cg*64 + (tid >> 2);
    const float* Cp; int loc;
    if(col < 512){ Cp = Cq; loc = col; }
    else if(col < 768){ Cp = Ck; loc = col - 512; }
    else if(col < 1024){ Cp = Cv; loc = col - 768; }
    else if(col < 1536){ Cp = Ce; loc = col - 1024; }
    else if(col < 2048){ Cp = C1; loc = col - 1536; }
    else { Cp = C2; loc = col - 2048; }
    const float4* wrow = (const float4*)(Cp + (size_t)loc*256 + q*64);
    float acc[8] = {0,0,0,0,0,0,0,0};
    #pragma unroll 4
    for(int i=0;i<16;++i){
      float4 w = wrow[i];
      #pragma unroll
      for(int k=0;k<8;++k){
        const float4 c = *(const float4*)(&cds[k][q*64 + i*4]);
        acc[k] += w.x*c.x + w.y*c.y + w.z*c.z + w.w*c.w;
      }
    }
    #pragma unroll
    for(int k=0;k<8;++k){
      acc[k] += __shfl_xor(acc[k], 1, 64);
      acc[k] += __shfl_xor(acc[k], 2, 64);
    }
    ws[WS_SCALE + (size_t)(bg*8 + q)*2560 + col]     = 1.0f + acc[q];
    ws[WS_SCALE + (size_t)(bg*8 + q + 4)*2560 + col] = 1.0f + acc[q+4];
  }
}

// ---------------- K2: receiver LN + q head-slice + t_k + cb (512 blocks = bu x h) ----------------
__global__ __launch_bounds__(256) void k_qt(const float* __restrict__ rst,
    const float* __restrict__ lg, const float* __restrict__ lb,
    const float* __restrict__ Wq, const float* __restrict__ bq,
    const float* __restrict__ Wk, const float* __restrict__ bk,
    float* __restrict__ ws){
  const int bu = blockIdx.x >> 3, h = blockIdx.x & 7;
  const int b = bu >> 5, u = bu & 31;
  const int r = (b*8 + h)*32 + u;
  const int tid = threadIdx.x, wave = tid>>6, lane = tid&63;
  __shared__ float xm[512];
  __shared__ float qv[64];
  __shared__ float red[4][65];
  __shared__ float rsm[4], rqm[4];
  float2 x2 = *(const float2*)(rst + (size_t)bu*512 + tid*2);
  float s = x2.x + x2.y, q = x2.x*x2.x + x2.y*x2.y;
  s = wsum(s); q = wsum(q);
  if(lane==0){ rsm[wave] = s; rqm[wave] = q; }
  __syncthreads();
  float S = rsm[0]+rsm[1]+rsm[2]+rsm[3];
  float Q = rqm[0]+rqm[1]+rqm[2]+rqm[3];
  float mu = S*(1.0f/512.0f);
  float rv = rsqrtf(Q*(1.0f/512.0f) - mu*mu + 1e-5f);
  const float* scal = ws + WS_SCALE + (size_t)bu*2560;
  xm[tid*2]   = ((x2.x-mu)*rv*lg[tid*2]   + lb[tid*2])   * scal[tid*2];
  xm[tid*2+1] = ((x2.y-mu)*rv*lg[tid*2+1] + lb[tid*2+1]) * scal[tid*2+1];
  __syncthreads();
  {
    const int o = tid & 63, sp = tid >> 6;
    const float4* wq = (const float4*)(Wq + (size_t)(h*64 + o)*512 + sp*128);
    const float* xp = xm + sp*128;
    float acc = 0.f;
    #pragma unroll 8
    for(int c4=0;c4<32;++c4){
      float4 w = wq[c4];
      acc += w.x*xp[c4*4] + w.y*xp[c4*4+1] + w.z*xp[c4*4+2] + w.w*xp[c4*4+3];
    }
    red[sp][o] = acc;
  }
  __syncthreads();
  if(tid < 64)
    qv[tid] = red[0][tid]+red[1][tid]+red[2][tid]+red[3][tid] + bq[h*64+tid];
  __syncthreads();
  if(tid < 64){
    float p = qv[tid] * bk[h*64+tid];
    p = wsum(p);
    if(tid==0) ws[WS_CB + r] = p;
  }
  {
    float acc = 0.f;
    #pragma unroll 4
    for(int d=0; d<64; ++d)
      acc += qv[d] * Wk[(size_t)(h*64+d)*256 + tid];
    ws[WS_T + (size_t)r*256 + tid] = acc * scal[512 + tid];
  }
}

// ---------------- K3: scores->exp->ctx v6: 8 rows/wave x 8 K-eighths, dbuf staging. 512 blocks x 512 thr ----------------
__global__ __launch_bounds__(512) void k_scctx(const float* __restrict__ Tm, float* __restrict__ ws){
  const int rg = blockIdx.x >> 3, vc = blockIdx.x & 7;   // 64 rowgroups(8) x 8 vchunks(256)
  const int r0 = rg * 8;
  const int b  = rg >> 5;
  const int v0 = vc * 256;
  const int tid = threadIdx.x, lane = tid & 63;
  const int wk = __builtin_amdgcn_readfirstlane(tid >> 6);   // 0..7: K-eighth / v-eighth
  const int i0 = lane * 4;
  const int srow = tid >> 6;
  const int sf   = (tid & 63) * 4;

  __shared__ float P[8][256];          // 8KB
  __shared__ float stg[2][32][256];    // 64KB (double-buffered staging + reduce regions)

  float4 a[8];
  #pragma unroll
  for(int j=0;j<8;++j) a[j] = make_float4(0,0,0,0);
  const float* Trow = Tm + (size_t)r0*256;   // wave-uniform

  // ================= phase 1: scores = T x sT =================
  const float* p1base = ws + WS_SLNT + (size_t)b*IN_*V_ + v0;
  float4 g0,g1,g2,g3;
  g0 = *(const float4*)(p1base + (size_t)(srow    )*V_ + sf);
  g1 = *(const float4*)(p1base + (size_t)(srow+ 8)*V_ + sf);
  g2 = *(const float4*)(p1base + (size_t)(srow+16)*V_ + sf);
  g3 = *(const float4*)(p1base + (size_t)(srow+24)*V_ + sf);
  for(int s=0; s<8; ++s){
    float (*sb)[256] = stg[s&1];
    *(float4*)&sb[srow   ][sf] = g0;
    *(float4*)&sb[srow+ 8][sf] = g1;
    *(float4*)&sb[srow+16][sf] = g2;
    *(float4*)&sb[srow+24][sf] = g3;
    if(s < 7){
      const float* nb = p1base + (size_t)(s+1)*32*V_;
      g0 = *(const float4*)(nb + (size_t)(srow    )*V_ + sf);
      g1 = *(const float4*)(nb + (size_t)(srow+ 8)*V_ + sf);
      g2 = *(const float4*)(nb + (size_t)(srow+16)*V_ + sf);
      g3 = *(const float4*)(nb + (size_t)(srow+24)*V_ + sf);
    }
    const int kg = s*32 + wk*4;   // uniform: this wave's 4 k-columns
    float4 t0 = *(const float4*)(Trow + 0*256 + kg);
    float4 t1 = *(const float4*)(Trow + 1*256 + kg);
    float4 t2 = *(const float4*)(Trow + 2*256 + kg);
    float4 t3 = *(const float4*)(Trow + 3*256 + kg);
    __syncthreads();   // sb ready; prior round's reads (other buffer) done
    const int kl = wk*4;
    float4 s0 = *(const float4*)&sb[kl+0][i0];
    float4 s1 = *(const float4*)&sb[kl+1][i0];
    float4 s2 = *(const float4*)&sb[kl+2][i0];
    float4 s3 = *(const float4*)&sb[kl+3][i0];
    FMA4(a[0],t0.x,s0) FMA4(a[0],t0.y,s1) FMA4(a[0],t0.z,s2) FMA4(a[0],t0.w,s3)
    FMA4(a[1],t1.x,s0) FMA4(a[1],t1.y,s1) FMA4(a[1],t1.z,s2) FMA4(a[1],t1.w,s3)
    FMA4(a[2],t2.x,s0) FMA4(a[2],t2.y,s1) FMA4(a[2],t2.z,s2) FMA4(a[2],t2.w,s3)
    FMA4(a[3],t3.x,s0) FMA4(a[3],t3.y,s1) FMA4(a[3],t3.z,s2) FMA4(a[3],t3.w,s3)
    t0 = *(const float4*)(Trow + 4*256 + kg);
    t1 = *(const float4*)(Trow + 5*256 + kg);
    t2 = *(const float4*)(Trow + 6*256 + kg);
    t3 = *(const float4*)(Trow + 7*256 + kg);
    FMA4(a[4],t0.x,s0) FMA4(a[4],t0.y,s1) FMA4(a[4],t0.z,s2) FMA4(a[4],t0.w,s3)
    FMA4(a[5],t1.x,s0) FMA4(a[5],t1.y,s1) FMA4(a[5],t1.z,s2) FMA4(a[5],t1.w,s3)
    FMA4(a[6],t2.x,s0) FMA4(a[6],t2.y,s1) FMA4(a[6],t2.z,s2) FMA4(a[6],t2.w,s3)
    FMA4(a[7],t3.x,s0) FMA4(a[7],t3.y,s1) FMA4(a[7],t3.z,s2) FMA4(a[7],t3.w,s3)
  }
  // ---- 8-way reduce: w0->P, w1..4->stg[0] quads, w5..6->stg[1][0:16), w7 finishes ----
  __syncthreads();
  if(wk == 0){
    #pragma unroll
    for(int j=0;j<8;++j) *(float4*)&P[j][i0] = a[j];
  } else if(wk <= 4){
    #pragma unroll
    for(int j=0;j<8;++j) *(float4*)&stg[0][(wk-1)*8 + j][i0] = a[j];
  } else if(wk <= 6){
    #pragma unroll
    for(int j=0;j<8;++j) *(float4*)&stg[1][(wk-5)*8 + j][i0] = a[j];
  }
  __syncthreads();
  if(wk == 7){
    #pragma unroll
    for(int j=0;j<8;++j){
      const int r = r0 + j;
      const float cb = ws[WS_CB + r];
      float4 q0 = *(const float4*)&P[j][i0];
      float4 q1 = *(const float4*)&stg[0][ 0+j][i0];
      float4 q2 = *(const float4*)&stg[0][ 8+j][i0];
      float4 q3 = *(const float4*)&stg[0][16+j][i0];
      float4 q4 = *(const float4*)&stg[0][24+j][i0];
      float4 q5 = *(const float4*)&stg[1][ 0+j][i0];
      float4 q6 = *(const float4*)&stg[1][ 8+j][i0];
      float4 e;
      e.x = __expf((a[j].x+q0.x+q1.x+q2.x+q3.x+q4.x+q5.x+q6.x+cb)*0.125f);
      e.y = __expf((a[j].y+q0.y+q1.y+q2.y+q3.y+q4.y+q5.y+q6.y+cb)*0.125f);
      e.z = __expf((a[j].z+q0.z+q1.z+q2.z+q3.z+q4.z+q5.z+q6.z+cb)*0.125f);
      e.w = __expf((a[j].w+q0.w+q1.w+q2.w+q3.w+q4.w+q5.w+q6.w+cb)*0.125f);
      *(float4*)&P[j][i0] = e;
      float ss = wsum(e.x+e.y+e.z+e.w);
      if(lane==0) ws[WS_SSUMP + (size_t)r*8 + vc] = ss;
    }
  }
  __syncthreads();   // P final; stg free

  // ================= phase 2: ctx = P x SL =================
  #pragma unroll
  for(int j=0;j<8;++j) a[j] = make_float4(0,0,0,0);
  const float* p2base = ws + WS_SLN + ((size_t)b*V_ + v0)*IN_;
  g0 = *(const float4*)(p2base + (size_t)(srow    )*IN_ + sf);
  g1 = *(const float4*)(p2base + (size_t)(srow+ 8)*IN_ + sf);
  g2 = *(const float4*)(p2base + (size_t)(srow+16)*IN_ + sf);
  g3 = *(const float4*)(p2base + (size_t)(srow+24)*IN_ + sf);
  for(int sv=0; sv<8; ++sv){
    float (*sb)[256] = stg[sv&1];
    *(float4*)&sb[srow   ][sf] = g0;
    *(float4*)&sb[srow+ 8][sf] = g1;
    *(float4*)&sb[srow+16][sf] = g2;
    *(float4*)&sb[srow+24][sf] = g3;
    if(sv < 7){
      const float* nb = p2base + (size_t)(sv+1)*32*IN_;
      g0 = *(const float4*)(nb + (size_t)(srow    )*IN_ + sf);
      g1 = *(const float4*)(nb + (size_t)(srow+ 8)*IN_ + sf);
      g2 = *(const float4*)(nb + (size_t)(srow+16)*IN_ + sf);
      g3 = *(const float4*)(nb + (size_t)(srow+24)*IN_ + sf);
    }
    __syncthreads();
    const int vl = wk*4, vg = sv*32 + vl;
    float4 s0 = *(const float4*)&sb[vl+0][i0];
    float4 s1 = *(const float4*)&sb[vl+1][i0];
    float4 s2 = *(const float4*)&sb[vl+2][i0];
    float4 s3 = *(const float4*)&sb[vl+3][i0];
    float4 p0 = *(const float4*)&P[0][vg];   // uniform -> LDS broadcast
    float4 p1 = *(const float4*)&P[1][vg];
    float4 p2 = *(const float4*)&P[2][vg];
    float4 p3 = *(const float4*)&P[3][vg];
    FMA4(a[0],p0.x,s0) FMA4(a[0],p0.y,s1) FMA4(a[0],p0.z,s2) FMA4(a[0],p0.w,s3)
    FMA4(a[1],p1.x,s0) FMA4(a[1],p1.y,s1) FMA4(a[1],p1.z,s2) FMA4(a[1],p1.w,s3)
    FMA4(a[2],p2.x,s0) FMA4(a[2],p2.y,s1) FMA4(a[2],p2.z,s2) FMA4(a[2],p2.w,s3)
    FMA4(a[3],p3.x,s0) FMA4(a[3],p3.y,s1) FMA4(a[3],p3.z,s2) FMA4(a[3],p3.w,s3)
    p0 = *(const float4*)&P[4][vg];
    p1 = *(const float4*)&P[5][vg];
    p2 = *(const float4*)&P[6][vg];
    p3 = *(const float4*)&P[7][vg];
    FMA4(a[4],p0.x,s0) FMA4(a[4],p0.y,s1) FMA4(a[4],p0.z,s2) FMA4(a[4],p0.w,s3)
    FMA4(a[5],p1.x,s0) FMA4(a[5],p1.y,s1) FMA4(a[5],p1.z,s2) FMA4(a[5],p1.w,s3)
    FMA4(a[6],p2.x,s0) FMA4(a[6],p2.y,s1) FMA4(a[6],p2.z,s2) FMA4(a[6],p2.w,s3)
    FMA4(a[7],p3.x,s0) FMA4(a[7],p3.y,s1) FMA4(a[7],p3.z,s2) FMA4(a[7],p3.w,s3)
  }
  // ---- 8-way reduce and store CTXP ----
  __syncthreads();
  if(wk == 0){
    #pragma unroll
    for(int j=0;j<8;++j) *(float4*)&P[j][i0] = a[j];
  } else if(wk <= 4){
    #pragma unroll
    for(int j=0;j<8;++j) *(float4*)&stg[0][(wk-1)*8 + j][i0] = a[j];
  } else if(wk <= 6){
    #pragma unroll
    for(int j=0;j<8;++j) *(float4*)&stg[1][(wk-5)*8 + j][i0] = a[j];
  }
  __syncthreads();
  if(wk == 7){
    #pragma unroll
    for(int j=0;j<8;++j){
      const int r = r0 + j;
      float4 q0 = *(const float4*)&P[j][i0];
      float4 q1 = *(const float4*)&stg[0][ 0+j][i0];
      float4 q2 = *(const float4*)&stg[0][ 8+j][i0];
      float4 q3 = *(const float4*)&stg[0][16+j][i0];
      float4 q4 = *(const float4*)&stg[0][24+j][i0];
      float4 q5 = *(const float4*)&stg[1][ 0+j][i0];
      float4 q6 = *(const float4*)&stg[1][ 8+j][i0];
      float4 d;
      d.x = a[j].x+q0.x+q1.x+q2.x+q3.x+q4.x+q5.x+q6.x;
      d.y = a[j].y+q0.y+q1.y+q2.y+q3.y+q4.y+q5.y+q6.y;
      d.z = a[j].z+q0.z+q1.z+q2.z+q3.z+q4.z+q5.z+q6.z;
      d.w = a[j].w+q0.w+q1.w+q2.w+q3.w+q4.w+q5.w+q6.w;
      *(float4*)(ws + WS_CTXP + ((size_t)vc*NR_ + r)*IN_ + i0) = d;
    }
  }
}

// ---------------- K4: msg+exit, column-split We -> AO partials (256 blocks = bu x st, 512 thr) ----------------
__global__ __launch_bounds__(512) void k_mexit(const float* __restrict__ Wv, const float* __restrict__ bv,
    const float* __restrict__ We, float* __restrict__ ws){
  const int bu = blockIdx.x >> 2, st = blockIdx.x & 3;
  const int b = bu >> 5, u = bu & 31;
  const int tid = threadIdx.x;
  __shared__ float xs[2][256];
  __shared__ float m2s[128];
  __shared__ float ps[4][128];
  __shared__ float invS[2];
  if(tid < 2){
    const int r = (b*8 + st*2 + tid)*32 + u;
    float v = 0.f;
    #pragma unroll
    for(int k=0;k<8;++k) v += ws[WS_SSUMP + (size_t)r*8 + k];
    invS[tid] = 1.0f / v;
  }
  {
    const int hh = tid >> 8, i = tid & 255;
    const int r = (b*8 + st*2 + hh)*32 + u;
    float s = 0.f;
    #pragma unroll
    for(int vcx=0; vcx<8; ++vcx)
      s += ws[WS_CTXP + ((size_t)vcx*NR_ + r)*IN_ + i];
    xs[hh][i] = s * ws[WS_SCALE + (size_t)bu*2560 + 768 + i];
  }
  __syncthreads();
  {
    const int lo = tid & 127, sp = tid >> 7;
    const int o = st*128 + lo;
    const float4* wv = (const float4*)(Wv + (size_t)o*256 + sp*64);
    const float* xp = &xs[lo>>6][sp*64];
    float acc = 0.f;
    #pragma unroll
    for(int c4=0;c4<16;++c4){
      float4 w = wv[c4];
      acc += w.x*xp[c4*4]+w.y*xp[c4*4+1]+w.z*xp[c4*4+2]+w.w*xp[c4*4+3];
    }
    ps[sp][lo] = acc;
  }
  __syncthreads();
  if(tid < 128){
    const int o = st*128 + tid;
    m2s[tid] = ((ps[0][tid]+ps[1][tid]+ps[2][tid]+ps[3][tid]) * invS[tid>>6] + bv[o])
               * ws[WS_SCALE + (size_t)bu*2560 + 1024 + o];
  }
  __syncthreads();
  {
    const float4* we = (const float4*)(We + (size_t)tid*512 + st*128);
    float acc = 0.f;
    #pragma unroll 8
    for(int c4=0;c4<32;++c4){
      float4 w = we[c4];
      acc += w.x*m2s[c4*4]+w.y*m2s[c4*4+1]+w.z*m2s[c4*4+2]+w.w*m2s[c4*4+3];
    }
    ws[WS_AOP + ((size_t)st*BU_ + bu)*512 + tid] = acc;
  }
}

// ---------------- K5: AO reduce + FFN layernorm + W1 + gelu + scale2 (256 blocks) ----------------
__global__ __launch_bounds__(256) void k_ffn1(const float* __restrict__ be, const float* __restrict__ lsa,
    const float* __restrict__ lg, const float* __restrict__ lb,
    const float* __restrict__ W1, const float* __restrict__ b1, float* __restrict__ ws){
  const int bu = blockIdx.x >> 2, ot = blockIdx.x & 3;
  const int tid = threadIdx.x, wave = tid>>6, lane = tid&63;
  __shared__ float xr[512];
  __shared__ float rsm[4], rqm[4];
  __shared__ float ps[2][128];
  const int s2 = tid*2;
  float2 x2;
  {
    const float* aop = ws + WS_AOP;
    float2 a0 = *(const float2*)(aop + ((size_t)0*BU_+bu)*512+s2);
    float2 a1 = *(const float2*)(aop + ((size_t)1*BU_+bu)*512+s2);
    float2 a2 = *(const float2*)(aop + ((size_t)2*BU_+bu)*512+s2);
    float2 a3 = *(const float2*)(aop + ((size_t)3*BU_+bu)*512+s2);
    x2.x = (a0.x+a1.x+a2.x+a3.x + be[s2])   * lsa[s2];
    x2.y = (a0.y+a1.y+a2.y+a3.y + be[s2+1]) * lsa[s2+1];
    *(float2*)(ws + WS_AO + (size_t)bu*512 + s2) = x2;
  }
  float s = x2.x+x2.y, q = x2.x*x2.x+x2.y*x2.y;
  s = wsum(s); q = wsum(q);
  if(lane==0){ rsm[wave]=s; rqm[wave]=q; }
  __syncthreads();
  float S=rsm[0]+rsm[1]+rsm[2]+rsm[3], Q=rqm[0]+rqm[1]+rqm[2]+rqm[3];
  float mu = S*(1.0f/512.0f);
  float rv = rsqrtf(Q*(1.0f/512.0f) - mu*mu + 1e-5f);
  const float* scal = ws + WS_SCALE + (size_t)bu*2560;
  xr[s2]   = ((x2.x-mu)*rv*lg[s2]   + lb[s2])   * scal[1536 + s2];
  xr[s2+1] = ((x2.y-mu)*rv*lg[s2+1] + lb[s2+1]) * scal[1536 + s2+1];
  __syncthreads();
  const int o = ot*128 + (tid & 127), sp = tid >> 7;
  const float4* w1 = (const float4*)(W1 + (size_t)o*512 + sp*256);
  const float* xp = xr + sp*256;
  float acc = 0.f;
  #pragma unroll 8
  for(int c4=0;c4<64;++c4){
    float4 w = w1[c4];
    acc += w.x*xp[c4*4]+w.y*xp[c4*4+1]+w.z*xp[c4*4+2]+w.w*xp[c4*4+3];
  }
  ps[sp][tid&127] = acc;
  __syncthreads();
  if(sp==0){
    float hh = ps[0][tid] + ps[1][tid] + b1[o];
    float ge = 0.5f*hh*(1.0f + erff(hh*0.70710678118654752f));
    ws[WS_H2 + (size_t)bu*512 + o] = ge * scal[2048 + o];
  }
}

// ---------------- K6: FFN W2 + residual -> out (256 blocks) ----------------
__global__ __launch_bounds__(256) void k_ffn2(const float* __restrict__ W2, const float* __restrict__ b2,
    const float* __restrict__ lsf, const float* __restrict__ ws, float* __restrict__ out){
  const int bu = blockIdx.x >> 2, st = blockIdx.x & 3;
  const int tid = threadIdx.x;
  const int s = st*128 + (tid & 127), sp = tid >> 7;
  __shared__ float ps[2][128];
  const float4* w2 = (const float4*)(W2 + (size_t)s*512 + sp*256);
  const float* hp = ws + WS_H2 + (size_t)bu*512 + sp*256;
  float acc = 0.f;
  #pragma unroll 8
  for(int c4=0;c4<64;++c4){
    float4 w = w2[c4];
    acc += w.x*hp[c4*4]+w.y*hp[c4*4+1]+w.z*hp[c4*4+2]+w.w*hp[c4*4+3];
  }
  ps[sp][tid&127] = acc;
  __syncthreads();
  if(sp==0)
    out[(size_t)bu*512 + s] = ws[WS_AO + (size_t)bu*512 + s]
                            + (ps[0][tid]+ps[1][tid] + b2[s]) * lsf[s];
}

extern "C" void kernel_launch(void* const* d_in, const int* in_sizes, int n_in,
                              void* d_out, int out_size, void* d_ws, size_t ws_size,
                              hipStream_t stream) {
  (void)in_sizes; (void)n_in; (void)out_size; (void)ws_size;
  const float* rst   = (const float*)d_in[0];
  const float* codes = (const float*)d_in[2];
  const float* snd   = (const float*)d_in[3];
  const float* ln_s_g = (const float*)d_in[4];
  const float* ln_s_b = (const float*)d_in[5];
  const float* ln_r_g = (const float*)d_in[6];
  const float* ln_r_b = (const float*)d_in[7];
  const float* Wq = (const float*)d_in[8];
  const float* bq = (const float*)d_in[9];
  const float* Cq = (const float*)d_in[10];
  const float* Wk = (const float*)d_in[11];
  const float* bk = (const float*)d_in[12];
  const float* Ck = (const float*)d_in[13];
  const float* Wv = (const float*)d_in[14];
  const float* bv = (const float*)d_in[15];
  const float* Cv = (const float*)d_in[16];
  const float* We = (const float*)d_in[17];
  const float* be = (const float*)d_in[18];
  const float* Ce = (const float*)d_in[19];
  const float* lsa = (const float*)d_in[20];
  const float* ln_f_g = (const float*)d_in[21];
  const float* ln_f_b = (const float*)d_in[22];
  const float* W1 = (const float*)d_in[23];
  const float* b1 = (const float*)d_in[24];
  const float* C1 = (const float*)d_in[25];
  const float* W2 = (const float*)d_in[26];
  const float* b2 = (const float*)d_in[27];
  const float* C2 = (const float*)d_in[28];
  const float* lsf = (const float*)d_in[29];
  float* ws  = (float*)d_ws;
  float* out = (float*)d_out;

  k_pre   <<<448, 256, 0, stream>>>(snd, ln_s_g, ln_s_b, codes, Cq, Ck, Cv, Ce, C1, C2, ws);
  k_qt    <<<512, 256, 0, stream>>>(rst, ln_r_g, ln_r_b, Wq, bq, Wk, bk, ws);
  k_scctx <<<512, 512, 0, stream>>>((const float*)(ws + WS_T), ws);
  k_mexit <<<256, 512, 0, stream>>>(Wv, bv, We, ws);
  k_ffn1  <<<256, 256, 0, stream>>>(be, lsa, ln_f_g, ln_f_b, W1, b1, ws);
  k_ffn2  <<<256, 256, 0, stream>>>(W2, b2, lsf, ws, out);
}

// Round 13
// 92.907 us; speedup vs baseline: 1.0293x; 1.0293x over previous
//
#include <hip/hip_runtime.h>
#include <math.h>

#define B_ 2
#define U_ 32
#define V_ 2048
#define IN_ 256
#define ST_ 512
#define H_ 8
#define BU_ 64
#define NR_ 512

// ws layout (float offsets)
#define WS_SLN   0u          // [B][V][IN]      1048576
#define WS_SLNT  1048576u    // [B][IN][V]      1048576
#define WS_SCALE 2097152u    // [BU][2560]      163840  (q:0 k:512 v:768 e:1024 f1:1536 f2:2048)
#define WS_T     2260992u    // [NR][IN]        131072
#define WS_CB    2392064u    // [NR]            512
#define WS_SSUMP 2392576u    // [NR][8]         4096
#define WS_CTXP  2396672u    // [8][NR][IN]     1048576
#define WS_AO    3445248u    // [BU][512]       32768
#define WS_H2    3478016u    // [BU][512]       32768
#define WS_AOP   3510784u    // [4][BU][512]    131072

__device__ __forceinline__ float wsum(float v){
  #pragma unroll
  for(int m=32;m>0;m>>=1) v += __shfl_xor(v, m, 64);
  return v;
}

#define FMA4(A, t, S) { A.x += (t)*(S).x; A.y += (t)*(S).y; A.z += (t)*(S).z; A.w += (t)*(S).w; }

// ---------------- K1: fused sender-LN+transpose (blocks 0..127) and scales GEMM (blocks 128..447) ----------------
__global__ __launch_bounds__(256) void k_pre(const float* __restrict__ snd,
    const float* __restrict__ g, const float* __restrict__ bb,
    const float* __restrict__ codes,
    const float* __restrict__ Cq, const float* __restrict__ Ck, const float* __restrict__ Cv,
    const float* __restrict__ Ce, const float* __restrict__ C1, const float* __restrict__ C2,
    float* __restrict__ ws){
  __shared__ float tile[32][261];
  __shared__ float cds[8][256];
  const int tid = threadIdx.x;
  if(blockIdx.x < 128){
    const int wave = tid>>6, lane = tid&63;
    const int rowbase = blockIdx.x * 32;
    const int b = rowbase >> 11, vloc = rowbase & 2047;
    float4 gg  = *(const float4*)(g  + lane*4);
    float4 bbv = *(const float4*)(bb + lane*4);
    for(int it=0; it<8; ++it){
      int rl = it*4 + wave;
      int r  = rowbase + rl;
      float4 x = *(const float4*)(snd + (size_t)r*IN_ + lane*4);
      float s = x.x+x.y+x.z+x.w;
      float q = x.x*x.x+x.y*x.y+x.z*x.z+x.w*x.w;
      s = wsum(s); q = wsum(q);
      float mu = s*(1.0f/256.0f);
      float rv = rsqrtf(q*(1.0f/256.0f) - mu*mu + 1e-5f);
      float4 y;
      y.x = (x.x-mu)*rv*gg.x + bbv.x;
      y.y = (x.y-mu)*rv*gg.y + bbv.y;
      y.z = (x.z-mu)*rv*gg.z + bbv.z;
      y.w = (x.w-mu)*rv*gg.w + bbv.w;
      *(float4*)(ws + WS_SLN + (size_t)r*IN_ + lane*4) = y;
      tile[rl][lane*4+0] = y.x;
      tile[rl][lane*4+1] = y.y;
      tile[rl][lane*4+2] = y.z;
      tile[rl][lane*4+3] = y.w;
    }
    __syncthreads();
    const int vh = tid & 31;
    const int ibase = (tid >> 5);
    for(int it=0; it<32; ++it){
      int i = it*8 + ibase;
      ws[WS_SLNT + ((size_t)b*IN_ + i)*V_ + vloc + vh] = tile[vh][i];
    }
  } else {
    const int idx = blockIdx.x - 128;
    const int cg = idx % 40, bg = idx / 40;
    #pragma unroll
    for(int j=0;j<8;++j){
      int fi = j*256 + tid;
      cds[fi>>8][fi&255] = codes[(size_t)(bg*8)*256 + fi];
    }
    __syncthreads();
    const int q = tid & 3;
    const int col = cg*64 + (tid >> 2);
    const float* Cp; int loc;
    if(col < 512){ Cp = Cq; loc = col; }
    else if(col < 768){ Cp = Ck; loc = col - 512; }
    else if(col < 1024){ Cp = Cv; loc = col - 768; }
    else if(col < 1536){ Cp = Ce; loc = col - 1024; }
    else if(col < 2048){ Cp = C1; loc = col - 1536; }
    else { Cp = C2; loc = col - 2048; }
    const float4* wrow = (const float4*)(Cp + (size_t)loc*256 + q*64);
    float acc[8] = {0,0,0,0,0,0,0,0};
    #pragma unroll 4
    for(int i=0;i<16;++i){
      float4 w = wrow[i];
      #pragma unroll
      for(int k=0;k<8;++k){
        const float4 c = *(const float4*)(&cds[k][q*64 + i*4]);
        acc[k] += w.x*c.x + w.y*c.y + w.z*c.z + w.w*c.w;
      }
    }
    #pragma unroll
    for(int k=0;k<8;++k){
      acc[k] += __shfl_xor(acc[k], 1, 64);
      acc[k] += __shfl_xor(acc[k], 2, 64);
    }
    ws[WS_SCALE + (size_t)(bg*8 + q)*2560 + col]     = 1.0f + acc[q];
    ws[WS_SCALE + (size_t)(bg*8 + q + 4)*2560 + col] = 1.0f + acc[q+4];
  }
}

// ---------------- K2: receiver LN + q + t_k + cb, 2 heads/block (256 blocks x 512 thr) ----------------
__global__ __launch_bounds__(512) void k_qt(const float* __restrict__ rst,
    const float* __restrict__ lg, const float* __restrict__ lb,
    const float* __restrict__ Wq, const float* __restrict__ bq,
    const float* __restrict__ Wk, const float* __restrict__ bk,
    float* __restrict__ ws){
  const int bu = blockIdx.x >> 2, hp = blockIdx.x & 3;
  const int b = bu >> 5, u = bu & 31;
  const int tid = threadIdx.x, lane = tid & 63, wave = tid >> 6;
  const int hh = tid >> 8, htid = tid & 255;       // head-half 0/1, local tid
  const int h = hp*2 + hh;
  const int r = (b*8 + h)*32 + u;
  __shared__ float xm[512];
  __shared__ float qv[2][64];
  __shared__ float red[2][4][65];
  __shared__ float rsm[8], rqm[8];
  // shared receiver LN (1 elem/thread across 512)
  float xv = rst[(size_t)bu*512 + tid];
  {
    float s = wsum(xv), q = wsum(xv*xv);
    if(lane==0){ rsm[wave] = s; rqm[wave] = q; }
  }
  __syncthreads();
  {
    float S=0.f, Q=0.f;
    #pragma unroll
    for(int k=0;k<8;++k){ S+=rsm[k]; Q+=rqm[k]; }
    float mu = S*(1.0f/512.0f);
    float rv = rsqrtf(Q*(1.0f/512.0f) - mu*mu + 1e-5f);
    xm[tid] = ((xv-mu)*rv*lg[tid] + lb[tid]) * ws[WS_SCALE + (size_t)bu*2560 + tid];
  }
  __syncthreads();
  // q slice for head h: 64 outputs, 4-way K split within each 256-thread half
  {
    const int o = htid & 63, sp = htid >> 6;
    const float4* wq = (const float4*)(Wq + (size_t)(h*64 + o)*512 + sp*128);
    const float* xp = xm + sp*128;
    float acc = 0.f;
    #pragma unroll 8
    for(int c4=0;c4<32;++c4){
      float4 w = wq[c4];
      acc += w.x*xp[c4*4] + w.y*xp[c4*4+1] + w.z*xp[c4*4+2] + w.w*xp[c4*4+3];
    }
    red[hh][sp][o] = acc;
  }
  __syncthreads();
  if(htid < 64)
    qv[hh][htid] = red[hh][0][htid]+red[hh][1][htid]+red[hh][2][htid]+red[hh][3][htid]
                 + bq[h*64+htid];
  __syncthreads();
  // cb: wave 0 (hh=0) and wave 4 (hh=1) handle their head
  if(htid < 64){
    float p = qv[hh][lane] * bk[h*64+lane];
    p = wsum(p);
    if(lane==0) ws[WS_CB + r] = p;
  }
  // T[r][i] = scale_k[i] * (qv_h . Wk_h[:,i])
  {
    float acc = 0.f;
    #pragma unroll 4
    for(int d=0; d<64; ++d)
      acc += qv[hh][d] * Wk[(size_t)(h*64+d)*256 + htid];
    ws[WS_T + (size_t)r*256 + htid] = acc * ws[WS_SCALE + (size_t)bu*2560 + 512 + htid];
  }
}

// ---------------- K3: scores->exp->ctx v5 (r11-validated): dbuf staging, 512 blocks x 512 thr ----------------
__global__ __launch_bounds__(512) void k_scctx(const float* __restrict__ Tm, float* __restrict__ ws){
  const int rg = blockIdx.x >> 3, vc = blockIdx.x & 7;   // 64 rowgroups(8) x 8 vchunks(256)
  const int r0 = rg * 8;
  const int b  = rg >> 5;
  const int v0 = vc * 256;
  const int tid = threadIdx.x, lane = tid & 63;
  const int w  = __builtin_amdgcn_readfirstlane(tid >> 6);
  const int wr = w & 1, wk = w >> 1;
  const int rw4 = wr * 4;
  const int i0 = lane * 4;
  const int srow = tid >> 6;
  const int sf   = (tid & 63) * 4;

  __shared__ float P[8][256];          // 8KB
  __shared__ float stg[2][32][256];    // 64KB (double-buffered staging)

  float4 a0={0,0,0,0},a1={0,0,0,0},a2={0,0,0,0},a3={0,0,0,0};
  const float* Trow = Tm + (size_t)(r0 + rw4)*256;   // wave-uniform base

  // ================= phase 1: scores = T x sT =================
  const float* p1base = ws + WS_SLNT + (size_t)b*IN_*V_ + v0;
  float4 g0,g1,g2,g3;
  g0 = *(const float4*)(p1base + (size_t)(srow    )*V_ + sf);
  g1 = *(const float4*)(p1base + (size_t)(srow+ 8)*V_ + sf);
  g2 = *(const float4*)(p1base + (size_t)(srow+16)*V_ + sf);
  g3 = *(const float4*)(p1base + (size_t)(srow+24)*V_ + sf);
  for(int s=0; s<8; ++s){
    float (*sb)[256] = stg[s&1];
    *(float4*)&sb[srow   ][sf] = g0;
    *(float4*)&sb[srow+ 8][sf] = g1;
    *(float4*)&sb[srow+16][sf] = g2;
    *(float4*)&sb[srow+24][sf] = g3;
    if(s < 7){
      const float* nb = p1base + (size_t)(s+1)*32*V_;
      g0 = *(const float4*)(nb + (size_t)(srow    )*V_ + sf);
      g1 = *(const float4*)(nb + (size_t)(srow+ 8)*V_ + sf);
      g2 = *(const float4*)(nb + (size_t)(srow+16)*V_ + sf);
      g3 = *(const float4*)(nb + (size_t)(srow+24)*V_ + sf);
    }
    const int kgA = s*32 + wk*8;       // uniform
    float4 tA[4], tB[4];
    #pragma unroll
    for(int j=0;j<4;++j) tA[j] = *(const float4*)(Trow + (size_t)j*256 + kgA);
    #pragma unroll
    for(int j=0;j<4;++j) tB[j] = *(const float4*)(Trow + (size_t)j*256 + kgA + 4);
    __syncthreads();   // sb written by all; prior-round reads (other buffer) already done
    {
      const int kl = wk*8;
      float4 s0 = *(const float4*)&sb[kl+0][i0];
      float4 s1 = *(const float4*)&sb[kl+1][i0];
      float4 s2 = *(const float4*)&sb[kl+2][i0];
      float4 s3 = *(const float4*)&sb[kl+3][i0];
      FMA4(a0,tA[0].x,s0) FMA4(a0,tA[0].y,s1) FMA4(a0,tA[0].z,s2) FMA4(a0,tA[0].w,s3)
      FMA4(a1,tA[1].x,s0) FMA4(a1,tA[1].y,s1) FMA4(a1,tA[1].z,s2) FMA4(a1,tA[1].w,s3)
      FMA4(a2,tA[2].x,s0) FMA4(a2,tA[2].y,s1) FMA4(a2,tA[2].z,s2) FMA4(a2,tA[2].w,s3)
      FMA4(a3,tA[3].x,s0) FMA4(a3,tA[3].y,s1) FMA4(a3,tA[3].z,s2) FMA4(a3,tA[3].w,s3)
    }
    {
      const int kl = wk*8 + 4;
      float4 s0 = *(const float4*)&sb[kl+0][i0];
      float4 s1 = *(const float4*)&sb[kl+1][i0];
      float4 s2 = *(const float4*)&sb[kl+2][i0];
      float4 s3 = *(const float4*)&sb[kl+3][i0];
      FMA4(a0,tB[0].x,s0) FMA4(a0,tB[0].y,s1) FMA4(a0,tB[0].z,s2) FMA4(a0,tB[0].w,s3)
      FMA4(a1,tB[1].x,s0) FMA4(a1,tB[1].y,s1) FMA4(a1,tB[1].z,s2) FMA4(a1,tB[1].w,s3)
      FMA4(a2,tB[2].x,s0) FMA4(a2,tB[2].y,s1) FMA4(a2,tB[2].z,s2) FMA4(a2,tB[2].w,s3)
      FMA4(a3,tB[3].x,s0) FMA4(a3,tB[3].y,s1) FMA4(a3,tB[3].z,s2) FMA4(a3,tB[3].w,s3)
    }
  }
  // ---- reduce 4 K-quarters: wk0->P, wk1->stg[0][0:8), wk2->stg[0][8:16), wk3 finishes ----
  __syncthreads();
  if(wk == 0){
    *(float4*)&P[rw4+0][i0]=a0; *(float4*)&P[rw4+1][i0]=a1;
    *(float4*)&P[rw4+2][i0]=a2; *(float4*)&P[rw4+3][i0]=a3;
  } else if(wk == 1){
    *(float4*)&stg[0][rw4+0][i0]=a0; *(float4*)&stg[0][rw4+1][i0]=a1;
    *(float4*)&stg[0][rw4+2][i0]=a2; *(float4*)&stg[0][rw4+3][i0]=a3;
  } else if(wk == 2){
    *(float4*)&stg[0][8+rw4+0][i0]=a0; *(float4*)&stg[0][8+rw4+1][i0]=a1;
    *(float4*)&stg[0][8+rw4+2][i0]=a2; *(float4*)&stg[0][8+rw4+3][i0]=a3;
  }
  __syncthreads();
  if(wk == 3){
    float4 av[4] = {a0,a1,a2,a3};
    #pragma unroll
    for(int j=0;j<4;++j){
      const int r = r0 + rw4 + j;
      const float cb = ws[WS_CB + r];
      float4 q0 = *(const float4*)&P[rw4+j][i0];
      float4 q1 = *(const float4*)&stg[0][rw4+j][i0];
      float4 q2 = *(const float4*)&stg[0][8+rw4+j][i0];
      float4 e;
      e.x = __expf((av[j].x+q0.x+q1.x+q2.x+cb)*0.125f);
      e.y = __expf((av[j].y+q0.y+q1.y+q2.y+cb)*0.125f);
      e.z = __expf((av[j].z+q0.z+q1.z+q2.z+cb)*0.125f);
      e.w = __expf((av[j].w+q0.w+q1.w+q2.w+cb)*0.125f);
      *(float4*)&P[rw4+j][i0] = e;
      float ss = wsum(e.x+e.y+e.z+e.w);
      if(lane==0) ws[WS_SSUMP + (size_t)r*8 + vc] = ss;
    }
  }
  __syncthreads();   // P final + stg fully free before phase 2 staging

  // ================= phase 2: ctx = P x SL =================
  a0=make_float4(0,0,0,0); a1=a0; a2=a0; a3=a0;
  const float* p2base = ws + WS_SLN + ((size_t)b*V_ + v0)*IN_;
  g0 = *(const float4*)(p2base + (size_t)(srow    )*IN_ + sf);
  g1 = *(const float4*)(p2base + (size_t)(srow+ 8)*IN_ + sf);
  g2 = *(const float4*)(p2base + (size_t)(srow+16)*IN_ + sf);
  g3 = *(const float4*)(p2base + (size_t)(srow+24)*IN_ + sf);
  for(int sv=0; sv<8; ++sv){
    float (*sb)[256] = stg[sv&1];
    *(float4*)&sb[srow   ][sf] = g0;
    *(float4*)&sb[srow+ 8][sf] = g1;
    *(float4*)&sb[srow+16][sf] = g2;
    *(float4*)&sb[srow+24][sf] = g3;
    if(sv < 7){
      const float* nb = p2base + (size_t)(sv+1)*32*IN_;
      g0 = *(const float4*)(nb + (size_t)(srow    )*IN_ + sf);
      g1 = *(const float4*)(nb + (size_t)(srow+ 8)*IN_ + sf);
      g2 = *(const float4*)(nb + (size_t)(srow+16)*IN_ + sf);
      g3 = *(const float4*)(nb + (size_t)(srow+24)*IN_ + sf);
    }
    __syncthreads();
    #pragma unroll
    for(int half=0; half<2; ++half){
      const int vl = wk*8 + half*4, vg = sv*32 + vl;
      float4 p0_ = *(const float4*)&P[rw4+0][vg];
      float4 p1_ = *(const float4*)&P[rw4+1][vg];
      float4 p2_ = *(const float4*)&P[rw4+2][vg];
      float4 p3_ = *(const float4*)&P[rw4+3][vg];
      float4 s0 = *(const float4*)&sb[vl+0][i0];
      float4 s1 = *(const float4*)&sb[vl+1][i0];
      float4 s2 = *(const float4*)&sb[vl+2][i0];
      float4 s3 = *(const float4*)&sb[vl+3][i0];
      FMA4(a0,p0_.x,s0) FMA4(a0,p0_.y,s1) FMA4(a0,p0_.z,s2) FMA4(a0,p0_.w,s3)
      FMA4(a1,p1_.x,s0) FMA4(a1,p1_.y,s1) FMA4(a1,p1_.z,s2) FMA4(a1,p1_.w,s3)
      FMA4(a2,p2_.x,s0) FMA4(a2,p2_.y,s1) FMA4(a2,p2_.z,s2) FMA4(a2,p2_.w,s3)
      FMA4(a3,p3_.x,s0) FMA4(a3,p3_.y,s1) FMA4(a3,p3_.z,s2) FMA4(a3,p3_.w,s3)
    }
  }
  // ---- reduce 4 v-quarters and store CTXP ----
  __syncthreads();
  if(wk == 0){
    *(float4*)&P[rw4+0][i0]=a0; *(float4*)&P[rw4+1][i0]=a1;
    *(float4*)&P[rw4+2][i0]=a2; *(float4*)&P[rw4+3][i0]=a3;
  } else if(wk == 1){
    *(float4*)&stg[0][rw4+0][i0]=a0; *(float4*)&stg[0][rw4+1][i0]=a1;
    *(float4*)&stg[0][rw4+2][i0]=a2; *(float4*)&stg[0][rw4+3][i0]=a3;
  } else if(wk == 2){
    *(float4*)&stg[0][8+rw4+0][i0]=a0; *(float4*)&stg[0][8+rw4+1][i0]=a1;
    *(float4*)&stg[0][8+rw4+2][i0]=a2; *(float4*)&stg[0][8+rw4+3][i0]=a3;
  }
  __syncthreads();
  if(wk == 3){
    float4 av[4] = {a0,a1,a2,a3};
    #pragma unroll
    for(int j=0;j<4;++j){
      const int r = r0 + rw4 + j;
      float4 q0 = *(const float4*)&P[rw4+j][i0];
      float4 q1 = *(const float4*)&stg[0][rw4+j][i0];
      float4 q2 = *(const float4*)&stg[0][8+rw4+j][i0];
      float4 d;
      d.x = av[j].x+q0.x+q1.x+q2.x;
      d.y = av[j].y+q0.y+q1.y+q2.y;
      d.z = av[j].z+q0.z+q1.z+q2.z;
      d.w = av[j].w+q0.w+q1.w+q2.w;
      *(float4*)(ws + WS_CTXP + ((size_t)vc*NR_ + r)*IN_ + i0) = d;
    }
  }
}

// ---------------- K4: msg+exit, column-split We -> AO partials (256 blocks = bu x st, 512 thr) ----------------
__global__ __launch_bounds__(512) void k_mexit(const float* __restrict__ Wv, const float* __restrict__ bv,
    const float* __restrict__ We, float* __restrict__ ws){
  const int bu = blockIdx.x >> 2, st = blockIdx.x & 3;
  const int b = bu >> 5, u = bu & 31;
  const int tid = threadIdx.x;
  __shared__ float xs[2][256];
  __shared__ float m2s[128];
  __shared__ float ps[4][128];
  __shared__ float invS[2];
  if(tid < 2){
    const int r = (b*8 + st*2 + tid)*32 + u;
    float v = 0.f;
    #pragma unroll
    for(int k=0;k<8;++k) v += ws[WS_SSUMP + (size_t)r*8 + k];
    invS[tid] = 1.0f / v;
  }
  {
    const int hh = tid >> 8, i = tid & 255;
    const int r = (b*8 + st*2 + hh)*32 + u;
    float s = 0.f;
    #pragma unroll
    for(int vcx=0; vcx<8; ++vcx)
      s += ws[WS_CTXP + ((size_t)vcx*NR_ + r)*IN_ + i];
    xs[hh][i] = s * ws[WS_SCALE + (size_t)bu*2560 + 768 + i];
  }
  __syncthreads();
  {
    const int lo = tid & 127, sp = tid >> 7;
    const int o = st*128 + lo;
    const float4* wv = (const float4*)(Wv + (size_t)o*256 + sp*64);
    const float* xp = &xs[lo>>6][sp*64];
    float acc = 0.f;
    #pragma unroll
    for(int c4=0;c4<16;++c4){
      float4 w = wv[c4];
      acc += w.x*xp[c4*4]+w.y*xp[c4*4+1]+w.z*xp[c4*4+2]+w.w*xp[c4*4+3];
    }
    ps[sp][lo] = acc;
  }
  __syncthreads();
  if(tid < 128){
    const int o = st*128 + tid;
    m2s[tid] = ((ps[0][tid]+ps[1][tid]+ps[2][tid]+ps[3][tid]) * invS[tid>>6] + bv[o])
               * ws[WS_SCALE + (size_t)bu*2560 + 1024 + o];
  }
  __syncthreads();
  {
    const float4* we = (const float4*)(We + (size_t)tid*512 + st*128);
    float acc = 0.f;
    #pragma unroll 8
    for(int c4=0;c4<32;++c4){
      float4 w = we[c4];
      acc += w.x*m2s[c4*4]+w.y*m2s[c4*4+1]+w.z*m2s[c4*4+2]+w.w*m2s[c4*4+3];
    }
    ws[WS_AOP + ((size_t)st*BU_ + bu)*512 + tid] = acc;
  }
}

// ---------------- K5: AO reduce + FFN layernorm + W1 + gelu + scale2 (256 blocks) ----------------
__global__ __launch_bounds__(256) void k_ffn1(const float* __restrict__ be, const float* __restrict__ lsa,
    const float* __restrict__ lg, const float* __restrict__ lb,
    const float* __restrict__ W1, const float* __restrict__ b1, float* __restrict__ ws){
  const int bu = blockIdx.x >> 2, ot = blockIdx.x & 3;
  const int tid = threadIdx.x, wave = tid>>6, lane = tid&63;
  __shared__ float xr[512];
  __shared__ float rsm[4], rqm[4];
  __shared__ float ps[2][128];
  const int s2 = tid*2;
  float2 x2;
  {
    const float* aop = ws + WS_AOP;
    float2 a0 = *(const float2*)(aop + ((size_t)0*BU_+bu)*512+s2);
    float2 a1 = *(const float2*)(aop + ((size_t)1*BU_+bu)*512+s2);
    float2 a2 = *(const float2*)(aop + ((size_t)2*BU_+bu)*512+s2);
    float2 a3 = *(const float2*)(aop + ((size_t)3*BU_+bu)*512+s2);
    x2.x = (a0.x+a1.x+a2.x+a3.x + be[s2])   * lsa[s2];
    x2.y = (a0.y+a1.y+a2.y+a3.y + be[s2+1]) * lsa[s2+1];
    *(float2*)(ws + WS_AO + (size_t)bu*512 + s2) = x2;
  }
  float s = x2.x+x2.y, q = x2.x*x2.x+x2.y*x2.y;
  s = wsum(s); q = wsum(q);
  if(lane==0){ rsm[wave]=s; rqm[wave]=q; }
  __syncthreads();
  float S=rsm[0]+rsm[1]+rsm[2]+rsm[3], Q=rqm[0]+rqm[1]+rqm[2]+rqm[3];
  float mu = S*(1.0f/512.0f);
  float rv = rsqrtf(Q*(1.0f/512.0f) - mu*mu + 1e-5f);
  const float* scal = ws + WS_SCALE + (size_t)bu*2560;
  xr[s2]   = ((x2.x-mu)*rv*lg[s2]   + lb[s2])   * scal[1536 + s2];
  xr[s2+1] = ((x2.y-mu)*rv*lg[s2+1] + lb[s2+1]) * scal[1536 + s2+1];
  __syncthreads();
  const int o = ot*128 + (tid & 127), sp = tid >> 7;
  const float4* w1 = (const float4*)(W1 + (size_t)o*512 + sp*256);
  const float* xp = xr + sp*256;
  float acc = 0.f;
  #pragma unroll 8
  for(int c4=0;c4<64;++c4){
    float4 w = w1[c4];
    acc += w.x*xp[c4*4]+w.y*xp[c4*4+1]+w.z*xp[c4*4+2]+w.w*xp[c4*4+3];
  }
  ps[sp][tid&127] = acc;
  __syncthreads();
  if(sp==0){
    float hh = ps[0][tid] + ps[1][tid] + b1[o];
    float ge = 0.5f*hh*(1.0f + erff(hh*0.70710678118654752f));
    ws[WS_H2 + (size_t)bu*512 + o] = ge * scal[2048 + o];
  }
}

// ---------------- K6: FFN W2 + residual -> out (256 blocks) ----------------
__global__ __launch_bounds__(256) void k_ffn2(const float* __restrict__ W2, const float* __restrict__ b2,
    const float* __restrict__ lsf, const float* __restrict__ ws, float* __restrict__ out){
  const int bu = blockIdx.x >> 2, st = blockIdx.x & 3;
  const int tid = threadIdx.x;
  const int s = st*128 + (tid & 127), sp = tid >> 7;
  __shared__ float ps[2][128];
  const float4* w2 = (const float4*)(W2 + (size_t)s*512 + sp*256);
  const float* hp = ws + WS_H2 + (size_t)bu*512 + sp*256;
  float acc = 0.f;
  #pragma unroll 8
  for(int c4=0;c4<64;++c4){
    float4 w = w2[c4];
    acc += w.x*hp[c4*4]+w.y*hp[c4*4+1]+w.z*hp[c4*4+2]+w.w*hp[c4*4+3];
  }
  ps[sp][tid&127] = acc;
  __syncthreads();
  if(sp==0)
    out[(size_t)bu*512 + s] = ws[WS_AO + (size_t)bu*512 + s]
                            + (ps[0][tid]+ps[1][tid] + b2[s]) * lsf[s];
}

extern "C" void kernel_launch(void* const* d_in, const int* in_sizes, int n_in,
                              void* d_out, int out_size, void* d_ws, size_t ws_size,
                              hipStream_t stream) {
  (void)in_sizes; (void)n_in; (void)out_size; (void)ws_size;
  const float* rst   = (const float*)d_in[0];
  const float* codes = (const float*)d_in[2];
  const float* snd   = (const float*)d_in[3];
  const float* ln_s_g = (const float*)d_in[4];
  const float* ln_s_b = (const float*)d_in[5];
  const float* ln_r_g = (const float*)d_in[6];
  const float* ln_r_b = (const float*)d_in[7];
  const float* Wq = (const float*)d_in[8];
  const float* bq = (const float*)d_in[9];
  const float* Cq = (const float*)d_in[10];
  const float* Wk = (const float*)d_in[11];
  const float* bk = (const float*)d_in[12];
  const float* Ck = (const float*)d_in[13];
  const float* Wv = (const float*)d_in[14];
  const float* bv = (const float*)d_in[15];
  const float* Cv = (const float*)d_in[16];
  const float* We = (const float*)d_in[17];
  const float* be = (const float*)d_in[18];
  const float* Ce = (const float*)d_in[19];
  const float* lsa = (const float*)d_in[20];
  const float* ln_f_g = (const float*)d_in[21];
  const float* ln_f_b = (const float*)d_in[22];
  const float* W1 = (const float*)d_in[23];
  const float* b1 = (const float*)d_in[24];
  const float* C1 = (const float*)d_in[25];
  const float* W2 = (const float*)d_in[26];
  const float* b2 = (const float*)d_in[27];
  const float* C2 = (const float*)d_in[28];
  const float* lsf = (const float*)d_in[29];
  float* ws  = (float*)d_ws;
  float* out = (float*)d_out;

  k_pre   <<<448, 256, 0, stream>>>(snd, ln_s_g, ln_s_b, codes, Cq, Ck, Cv, Ce, C1, C2, ws);
  k_qt    <<<256, 512, 0, stream>>>(rst, ln_r_g, ln_r_b, Wq, bq, Wk, bk, ws);
  k_scctx <<<512, 512, 0, stream>>>((const float*)(ws + WS_T), ws);
  k_mexit <<<256, 512, 0, stream>>>(Wv, bv, We, ws);
  k_ffn1  <<<256, 256, 0, stream>>>(be, lsa, ln_f_g, ln_f_b, W1, b1, ws);
  k_ffn2  <<<256, 256, 0, stream>>>(W2, b2, lsf, ws, out);
}